// Round 1
// baseline (360.792 us; speedup 1.0000x reference)
//
#include <hip/hip_runtime.h>
#include <hip/hip_bf16.h>
#include <math.h>

#define S_LEN 4096
#define HID   1280
#define NH    16
#define HD    80
#define HDP   96
#define N3    3840

typedef __bf16 bf16_t;
typedef __bf16 bf16x8 __attribute__((ext_vector_type(8)));
typedef float  f32x4  __attribute__((ext_vector_type(4)));

// ---------------- prep kernels ----------------

__global__ void k_f2bf(const float* __restrict__ in, bf16_t* __restrict__ out, int n){
  int i = blockIdx.x * blockDim.x + threadIdx.x;
  int stride = gridDim.x * blockDim.x;
  for (; i < n; i += stride) out[i] = (bf16_t)in[i];
}

// out[n*K + k] = (bf16) in[k*N + n]   (in: K x N row-major -> out: N x K row-major)
__global__ void k_transpose_bf(const float* __restrict__ in, bf16_t* __restrict__ out, int K, int N){
  size_t i = (size_t)blockIdx.x * blockDim.x + threadIdx.x;
  size_t total = (size_t)K * N;
  size_t stride = (size_t)gridDim.x * blockDim.x;
  for (; i < total; i += stride){
    size_t n = i / (size_t)K, k = i % (size_t)K;
    out[i] = (bf16_t)in[k * (size_t)N + n];
  }
}

// searchsorted(cu, s, side='right') -> seg id; plus segment [lo,hi) bounds per row
__global__ void k_seg(const int* __restrict__ cu, int* __restrict__ seg,
                      int* __restrict__ rlo, int* __restrict__ rhi){
  int s = blockIdx.x * blockDim.x + threadIdx.x;
  if (s >= S_LEN) return;
  int c = 0;
  #pragma unroll
  for (int j = 0; j < 9; ++j) c += (cu[j] <= s) ? 1 : 0;
  seg[s] = c;            // c in [1,8]
  rlo[s] = cu[c - 1];    // cu[c-1] <= s < cu[c]
  rhi[s] = cu[c];
}

// ---------------- GEMM: C[m][n] = sum_k A[m][k] * Bt[n][k] + bias[n] ----------------
// 128x128 tile, BK=32, 4 waves (2x2), 16x16x32 bf16 MFMA. Reg-staged LDS (round 1).
template<bool OUT_BF16>
__global__ __launch_bounds__(256) void k_gemm(const bf16_t* __restrict__ A, const bf16_t* __restrict__ Bt,
                                              const float* __restrict__ bias, void* __restrict__ outp,
                                              int M, int N, int K){
  __shared__ bf16_t sA[128 * 32];
  __shared__ bf16_t sB[128 * 32];
  const int tid  = threadIdx.x;
  const int lane = tid & 63;
  const int wave = tid >> 6;
  const int wr = wave >> 1, wc = wave & 1;
  const int g = lane >> 4, l16 = lane & 15;
  const int m0 = blockIdx.y * 128, n0 = blockIdx.x * 128;

  f32x4 acc[4][4] = {};

  // staging chunk assignment: chunk c (16B) -> row c>>2, col-slot c&3 (row-major [128][32])
  const int c0 = tid, c1 = 256 + tid;
  const int ar0 = c0 >> 2, ak0 = (c0 & 3) * 8;
  const int ar1 = c1 >> 2, ak1 = (c1 & 3) * 8;

  for (int k0 = 0; k0 < K; k0 += 32){
    bf16x8 a0 = *(const bf16x8*)(A  + (size_t)(m0 + ar0) * K + k0 + ak0);
    bf16x8 a1 = *(const bf16x8*)(A  + (size_t)(m0 + ar1) * K + k0 + ak1);
    bf16x8 b0 = *(const bf16x8*)(Bt + (size_t)(n0 + ar0) * K + k0 + ak0);
    bf16x8 b1 = *(const bf16x8*)(Bt + (size_t)(n0 + ar1) * K + k0 + ak1);
    __syncthreads();   // previous iteration's fragment reads done
    *(bf16x8*)(sA + c0 * 8) = a0;
    *(bf16x8*)(sA + c1 * 8) = a1;
    *(bf16x8*)(sB + c0 * 8) = b0;
    *(bf16x8*)(sB + c1 * 8) = b1;
    __syncthreads();
    bf16x8 af[4], bfv[4];
    #pragma unroll
    for (int mi = 0; mi < 4; ++mi) af[mi]  = *(const bf16x8*)(sA + (wr * 64 + mi * 16 + l16) * 32 + g * 8);
    #pragma unroll
    for (int ni = 0; ni < 4; ++ni) bfv[ni] = *(const bf16x8*)(sB + (wc * 64 + ni * 16 + l16) * 32 + g * 8);
    #pragma unroll
    for (int mi = 0; mi < 4; ++mi)
      #pragma unroll
      for (int ni = 0; ni < 4; ++ni)
        acc[mi][ni] = __builtin_amdgcn_mfma_f32_16x16x32_bf16(af[mi], bfv[ni], acc[mi][ni], 0, 0, 0);
  }

  // epilogue: D layout col=lane&15, row=(lane>>4)*4+reg  [m89/m91]
  #pragma unroll
  for (int ni = 0; ni < 4; ++ni){
    const int col = n0 + wc * 64 + ni * 16 + l16;
    const float bv = bias[col];
    #pragma unroll
    for (int mi = 0; mi < 4; ++mi){
      const int row = m0 + wr * 64 + mi * 16 + g * 4;
      #pragma unroll
      for (int r = 0; r < 4; ++r){
        float v = acc[mi][ni][r] + bv;
        if (OUT_BF16) ((bf16_t*)outp)[(size_t)(row + r) * N + col] = (bf16_t)v;
        else          ((float*) outp)[(size_t)(row + r) * N + col] = v;
      }
    }
  }
}

// ---------------- RoPE + head-major repack of q,k (zero-padded d in [80,96)) ----------------
__global__ void k_rope(const bf16_t* __restrict__ qkv, const float* __restrict__ rope,
                       bf16_t* __restrict__ q_t, bf16_t* __restrict__ k_t){
  const int s = blockIdx.x;
  const int tid = threadIdx.x;
  const size_t base = (size_t)s * N3;
  for (int i = tid; i < HID; i += 256){
    const int h = i / HD, d = i % HD;
    const int dm = (d < 40) ? d : d - 40;
    float sn, cs;
    sincosf(rope[s * 40 + dm], &sn, &cs);
    const int i2 = (d < 40) ? i + 40 : i - 40;
    float qv = (float)qkv[base + i];
    float kv = (float)qkv[base + HID + i];
    float q2 = (float)qkv[base + i2];
    float k2 = (float)qkv[base + HID + i2];
    float sg = (d < 40) ? -1.f : 1.f;
    size_t o = ((size_t)h * S_LEN + s) * HDP + d;
    q_t[o] = (bf16_t)(qv * cs + sg * q2 * sn);
    k_t[o] = (bf16_t)(kv * cs + sg * k2 * sn);
  }
  for (int i = tid; i < NH * 16; i += 256){
    const int h = i >> 4, d = HD + (i & 15);
    size_t o = ((size_t)h * S_LEN + s) * HDP + d;
    q_t[o] = (bf16_t)0.f;
    k_t[o] = (bf16_t)0.f;
  }
}

// ---------------- V transpose: v_T[h][d][s] = v[s][h][d] (only d<80 written/read) ----------------
__global__ __launch_bounds__(256) void k_vtrans(const bf16_t* __restrict__ qkv, bf16_t* __restrict__ v_T){
  const int h  = blockIdx.z;
  const int d0 = blockIdx.y * 16;
  const int s0 = blockIdx.x * 64;
  __shared__ bf16_t tile[64][17];
  const int tid = threadIdx.x;
  const int dl = tid & 15, sl = tid >> 4;
  #pragma unroll
  for (int p = 0; p < 4; ++p){
    int s = s0 + p * 16 + sl;
    tile[p * 16 + sl][dl] = qkv[(size_t)s * N3 + 2 * HID + h * HD + d0 + dl];
  }
  __syncthreads();
  const int s2 = tid & 63, d2 = tid >> 6;
  #pragma unroll
  for (int p = 0; p < 4; ++p){
    int d = p * 4 + d2;
    v_T[((size_t)h * HDP + d0 + d) * S_LEN + s0 + s2] = tile[s2][d];
  }
}

// ---------------- flash attention with block-diagonal segment mask ----------------
// 1 wave per block: 16 q-rows of one head. kv blocks of 32 within segment span.
__global__ __launch_bounds__(64) void k_attn(const bf16_t* __restrict__ q_t, const bf16_t* __restrict__ k_t,
                                             const bf16_t* __restrict__ v_T, const int* __restrict__ seg,
                                             const int* __restrict__ rlo, const int* __restrict__ rhi,
                                             bf16_t* __restrict__ attn){
  const int qb = blockIdx.x, h = blockIdx.y;
  const int q0 = qb * 16;
  const int lane = threadIdx.x;
  const int g = lane >> 4, l16 = lane & 15;
  const size_t hq = (size_t)h * S_LEN;
  const float SCALE = 0.11180339887498949f; // 1/sqrt(80)

  bf16x8 qf[3];
  #pragma unroll
  for (int c = 0; c < 3; ++c)
    qf[c] = *(const bf16x8*)(q_t + (hq + q0 + l16) * HDP + c * 32 + g * 8);

  int sq[4];
  #pragma unroll
  for (int r = 0; r < 4; ++r) sq[r] = seg[q0 + g * 4 + r];
  const int lo = rlo[q0], hi = rhi[q0 + 15];

  float m_run[4] = {-1e30f, -1e30f, -1e30f, -1e30f};
  float l_run[4] = {0.f, 0.f, 0.f, 0.f};
  f32x4 acc[5] = {};
  __shared__ bf16_t sP[16 * 32];

  for (int kv0 = (lo & ~31); kv0 < hi; kv0 += 32){
    f32x4 sc[2];
    int sk[2];
    #pragma unroll
    for (int j = 0; j < 2; ++j){
      f32x4 t = {0.f, 0.f, 0.f, 0.f};
      #pragma unroll
      for (int c = 0; c < 3; ++c){
        bf16x8 kf = *(const bf16x8*)(k_t + (hq + kv0 + j * 16 + l16) * HDP + c * 32 + g * 8);
        t = __builtin_amdgcn_mfma_f32_16x16x32_bf16(qf[c], kf, t, 0, 0, 0);
      }
      sc[j] = t;
      sk[j] = seg[kv0 + j * 16 + l16];
    }
    // mask + scale; D: col(kv)=lane&15, row(q)=g*4+r
    float p[2][4], mx[4];
    #pragma unroll
    for (int r = 0; r < 4; ++r){
      float a = (sq[r] == sk[0]) ? sc[0][r] * SCALE : -1e30f;
      float b = (sq[r] == sk[1]) ? sc[1][r] * SCALE : -1e30f;
      p[0][r] = a; p[1][r] = b;
      float v = fmaxf(a, b);
      v = fmaxf(v, __shfl_xor(v, 1, 16));
      v = fmaxf(v, __shfl_xor(v, 2, 16));
      v = fmaxf(v, __shfl_xor(v, 4, 16));
      v = fmaxf(v, __shfl_xor(v, 8, 16));
      mx[r] = v;
    }
    float fr[4];
    #pragma unroll
    for (int r = 0; r < 4; ++r){
      float mn = fmaxf(m_run[r], mx[r]);
      fr[r] = __expf(m_run[r] - mn);   // -1e30-(-1e30)=0 -> 1 (all-masked ok); else underflows to 0
      m_run[r] = mn;
      float p0 = (p[0][r] > -1e29f) ? __expf(p[0][r] - mn) : 0.f;
      float p1 = (p[1][r] > -1e29f) ? __expf(p[1][r] - mn) : 0.f;
      p[0][r] = p0; p[1][r] = p1;
      float s2 = p0 + p1;
      s2 += __shfl_xor(s2, 1, 16);
      s2 += __shfl_xor(s2, 2, 16);
      s2 += __shfl_xor(s2, 4, 16);
      s2 += __shfl_xor(s2, 8, 16);
      l_run[r] = l_run[r] * fr[r] + s2;
    }
    #pragma unroll
    for (int ni = 0; ni < 5; ++ni)
      #pragma unroll
      for (int r = 0; r < 4; ++r)
        acc[ni][r] *= fr[r];
    // P (row=q=g*4+r, col=kv=j*16+l16) -> LDS -> A-fragment (row=q=l16, k=kv=g*8+e)
    #pragma unroll
    for (int j = 0; j < 2; ++j)
      #pragma unroll
      for (int r = 0; r < 4; ++r)
        sP[(g * 4 + r) * 32 + j * 16 + l16] = (bf16_t)p[j][r];
    __syncthreads();
    bf16x8 pa = *(const bf16x8*)(sP + l16 * 32 + g * 8);
    __syncthreads();
    #pragma unroll
    for (int ni = 0; ni < 5; ++ni){
      bf16x8 vf = *(const bf16x8*)(v_T + ((size_t)h * HDP + ni * 16 + l16) * S_LEN + kv0 + g * 8);
      acc[ni] = __builtin_amdgcn_mfma_f32_16x16x32_bf16(pa, vf, acc[ni], 0, 0, 0);
    }
  }
  #pragma unroll
  for (int ni = 0; ni < 5; ++ni){
    #pragma unroll
    for (int r = 0; r < 4; ++r){
      float o = acc[ni][r] / l_run[r];
      attn[(size_t)(q0 + g * 4 + r) * HID + h * HD + ni * 16 + l16] = (bf16_t)o;
    }
  }
}

// ---------------- launch ----------------

extern "C" void kernel_launch(void* const* d_in, const int* in_sizes, int n_in,
                              void* d_out, int out_size, void* d_ws, size_t ws_size,
                              hipStream_t stream){
  const float* x    = (const float*)d_in[0];
  const float* rope = (const float*)d_in[1];
  const int*   cu   = (const int*)  d_in[2];
  const float* wqkv = (const float*)d_in[3];
  const float* bqkv = (const float*)d_in[4];
  const float* wo   = (const float*)d_in[5];
  const float* bo   = (const float*)d_in[6];
  float* out = (float*)d_out;

  char* ws = (char*)d_ws;
  size_t off = 0;
  auto alloc = [&](size_t bytes) -> void* {
    void* p = ws + off;
    off += (bytes + 255) & ~(size_t)255;
    return p;
  };
  bf16_t* x_bf   = (bf16_t*)alloc((size_t)S_LEN * HID * 2);
  bf16_t* w_t    = (bf16_t*)alloc((size_t)N3 * HID * 2);
  bf16_t* wo_t   = (bf16_t*)alloc((size_t)HID * HID * 2);
  bf16_t* qkv_bf = (bf16_t*)alloc((size_t)S_LEN * N3 * 2);
  bf16_t* q_t    = (bf16_t*)alloc((size_t)NH * S_LEN * HDP * 2);
  bf16_t* k_t    = (bf16_t*)alloc((size_t)NH * S_LEN * HDP * 2);
  bf16_t* v_T    = (bf16_t*)alloc((size_t)NH * HDP * S_LEN * 2);
  int* seg = (int*)alloc(S_LEN * 4);
  int* rlo = (int*)alloc(S_LEN * 4);
  int* rhi = (int*)alloc(S_LEN * 4);
  bf16_t* attn_bf = x_bf;  // alias: x_bf dead after QKV GEMM (total ws ~93 MB)

  k_f2bf<<<2048, 256, 0, stream>>>(x, x_bf, S_LEN * HID);
  k_transpose_bf<<<2048, 256, 0, stream>>>(wqkv, w_t, HID, N3);
  k_transpose_bf<<<2048, 256, 0, stream>>>(wo, wo_t, HID, HID);
  k_seg<<<16, 256, 0, stream>>>(cu, seg, rlo, rhi);

  k_gemm<true><<<dim3(N3 / 128, S_LEN / 128), 256, 0, stream>>>(x_bf, w_t, bqkv, qkv_bf, S_LEN, N3, HID);

  k_rope<<<S_LEN, 256, 0, stream>>>(qkv_bf, rope, q_t, k_t);
  k_vtrans<<<dim3(S_LEN / 64, 5, NH), 256, 0, stream>>>(qkv_bf, v_T);

  k_attn<<<dim3(S_LEN / 16, NH), 64, 0, stream>>>(q_t, k_t, v_T, seg, rlo, rhi, attn_bf);

  k_gemm<false><<<dim3(HID / 128, S_LEN / 128), 256, 0, stream>>>(attn_bf, wo_t, bo, out, S_LEN, HID, HID);
}